// Round 13
// baseline (867.701 us; speedup 1.0000x reference)
//
#include <hip/hip_runtime.h>
#include <hip/hip_bf16.h>
#include <math.h>
#include <string.h>

static constexpr int TT = 16384;
static constexpr int DD = 1024;
static constexpr int FF = 2048;
static constexpr int VV = 4096;
static constexpr int CAP = 1024;       // borderline-token capacity (exp ~190)
#define TAU 0.02f                      // |logit| flag threshold

using bf16 = __hip_bfloat16;
typedef __attribute__((ext_vector_type(8))) short bf16x8;
typedef __attribute__((ext_vector_type(4))) float f32x4;

__device__ inline void gload16(const void* g, void* l) {
    __builtin_amdgcn_global_load_lds(
        (const __attribute__((address_space(1))) void*)g,
        (__attribute__((address_space(3))) void*)l, 16, 0, 0);
}

// ===========================================================================
// 8-phase 256x256 MFMA GEMM (round-4/7/10 verified schedule, BK=64).
// A [M,K] bf16 row-major, BT [N,K] bf16 (B^T). 512 thr = 8 waves (2M x 4N),
// per-wave out 128x64 (8 mf x 4 nf frags of 16x16x32). BK=64, 2 K-tiles/iter.
// LDS 128 KiB: buf{0,1} x {A[256][64] | B[256][64]}. Stage stream: half j,
// tile=j>>2, part order {B h0, B h1, A h0, A h1}; vmcnt(6) at phases A3/B3.
// EPI: 0 none, 1 relu, 3 +Xbf16.
// MTILE: consecutive N-tiles per block (persistent-block; grid.x = N/256/MTILE)
// -> every GEMM is one 256-block round; tile t+1 prologue overlaps tile t
//    epilogue store-drain per-wave instead of a grid-wide boundary.
// ===========================================================================
template<int EPI, bool WB16, bool WF32, bool ROWLIM, bool GPART, int MTILE>
__global__ __launch_bounds__(512, 2)
void mgemm8(const bf16* __restrict__ A, const bf16* __restrict__ BT,
            const bf16* __restrict__ Xh,
            bf16* __restrict__ Ob, float* __restrict__ Of,
            float* __restrict__ gpart, const float* __restrict__ qv,
            int M, int N, int K, const int* __restrict__ rowlim)
{
    if constexpr (ROWLIM) { if ((int)blockIdx.y * 256 >= *rowlim) return; }
    const int m0 = blockIdx.y * 256;

    extern __shared__ char smem[];   // 2 bufs x (A 32K | B 32K) = 128 KiB

    const int tid = threadIdx.x;
    const int wv = tid >> 6, ln = tid & 63;
    const int wm = wv >> 2, wn = wv & 3;
    const int lr = ln & 15, lk = ln >> 4;
    const int swz = (lr & 7) << 4;

    const bf16* Ag = A + (size_t)m0 * K;

    const int NT = K >> 6;
    const int NI = NT >> 1;

    const int aoff0 = (wm * 128 + lr) * 128;
    const int boff0 = 32768 + (wn * 64 + lr) * 128;
    const int cb0 = (lk * 16) ^ swz;
    const int cb1 = (64 + lk * 16) ^ swz;

    bf16x8 afr[2][2], bfr[4][2];
    f32x4 acc[8][4];

#define DS_A(BUF, Q) do {                                                     \
    const char* _p = smem + (BUF) * 65536 + aoff0 + (Q) * 4096;               \
    afr[0][0] = *(const bf16x8*)(_p + cb0);                                   \
    afr[0][1] = *(const bf16x8*)(_p + cb1);                                   \
    afr[1][0] = *(const bf16x8*)(_p + 2048 + cb0);                            \
    afr[1][1] = *(const bf16x8*)(_p + 2048 + cb1);                            \
} while (0)

#define DS_B(BUF) do {                                                        \
    const char* _p = smem + (BUF) * 65536 + boff0;                            \
    _Pragma("unroll")                                                         \
    for (int nf = 0; nf < 4; ++nf) {                                          \
        bfr[nf][0] = *(const bf16x8*)(_p + nf * 2048 + cb0);                  \
        bfr[nf][1] = *(const bf16x8*)(_p + nf * 2048 + cb1);                  \
    }                                                                         \
} while (0)

#define MFMAQ(Q) do {                                                         \
    __builtin_amdgcn_s_setprio(1);                                            \
    _Pragma("unroll")                                                         \
    for (int m2 = 0; m2 < 2; ++m2)                                            \
        _Pragma("unroll")                                                     \
        for (int nf = 0; nf < 4; ++nf) {                                      \
            acc[(Q) * 2 + m2][nf] = __builtin_amdgcn_mfma_f32_16x16x32_bf16(  \
                afr[m2][0], bfr[nf][0], acc[(Q) * 2 + m2][nf], 0, 0, 0);      \
            acc[(Q) * 2 + m2][nf] = __builtin_amdgcn_mfma_f32_16x16x32_bf16(  \
                afr[m2][1], bfr[nf][1], acc[(Q) * 2 + m2][nf], 0, 0, 0);      \
        }                                                                     \
    __builtin_amdgcn_s_setprio(0);                                            \
} while (0)

// W: 0 = no wait, 1 = vmcnt(6), 2 = vmcnt(0)
#define PHASE(Q, BUF, DOB, J, W)                                              \
    {                                                                         \
        DS_A(BUF, Q);                                                         \
        if (DOB) DS_B(BUF);                                                   \
        stage_j(J);                                                           \
        if ((W) == 1)      asm volatile("s_waitcnt vmcnt(6)" ::: "memory");   \
        else if ((W) == 2) asm volatile("s_waitcnt vmcnt(0)" ::: "memory");   \
        __builtin_amdgcn_sched_barrier(0);                                    \
        __builtin_amdgcn_s_barrier();                                         \
        MFMAQ(Q);                                                             \
        __builtin_amdgcn_s_barrier();                                         \
    }

    for (int tt = 0; tt < MTILE; ++tt) {
        const int bxt = blockIdx.x * MTILE + tt;
        const int n0 = bxt * 256;
        const bf16* Bg = BT + (size_t)n0 * K;

        auto STAGE = [&](const bf16* g, int h, int kt, int buf, int op) {
            const int r = ln >> 3;
            const int c = ((ln & 7) ^ r) * 8;
            const bf16* s = g + (size_t)(h * 128 + wv * 16 + r) * K + kt * 64 + c;
            char* d = smem + buf * 65536 + op * 32768 + h * 16384 + wv * 2048;
            gload16(s, d);
            gload16(s + (size_t)8 * K, d + 1024);
        };
        auto stage_j = [&](int j) {
            const int tile = j >> 2;
            if (tile >= NT) return;
            const int part = j & 3;
            const int buf = tile & 1;
            if (part < 2) STAGE(Bg, part, tile, buf, 1);
            else          STAGE(Ag, part - 2, tile, buf, 0);
        };

        #pragma unroll
        for (int m = 0; m < 8; ++m)
            #pragma unroll
            for (int n = 0; n < 4; ++n) acc[m][n] = (f32x4){0.f, 0.f, 0.f, 0.f};

        // prologue — tile0 {Bh0,Bh1,Ah0,Ah1} -> buf0, vmcnt(4);
        // tile1 {Bh0,Bh1,Ah0} -> buf1, vmcnt(6); barrier.
        STAGE(Bg, 0, 0, 0, 1); STAGE(Bg, 1, 0, 0, 1);
        STAGE(Ag, 0, 0, 0, 0); STAGE(Ag, 1, 0, 0, 0);
        asm volatile("s_waitcnt vmcnt(4)" ::: "memory");
        STAGE(Bg, 0, 1, 1, 1); STAGE(Bg, 1, 1, 1, 1);
        STAGE(Ag, 0, 1, 1, 0);
        asm volatile("s_waitcnt vmcnt(6)" ::: "memory");
        __builtin_amdgcn_sched_barrier(0);
        __builtin_amdgcn_s_barrier();

        for (int i = 0; i < NI; ++i) {
            const int jb = 7 + 8 * i;
            const bool last = (i + 1 == NI);
            PHASE(0, 0, true,  jb + 0, 0);
            PHASE(1, 0, false, jb + 1, 0);
            PHASE(2, 0, false, jb + 2, 0);
            PHASE(3, 0, false, jb + 3, last ? 2 : 1);
            PHASE(0, 1, true,  jb + 4, 0);
            PHASE(1, 1, false, jb + 5, 0);
            PHASE(2, 1, false, jb + 6, 0);
            PHASE(3, 1, false, jb + 7, last ? 0 : 1);
        }

        if constexpr (GPART) {
            float qvv[4];
            #pragma unroll
            for (int nf = 0; nf < 4; ++nf) qvv[nf] = qv[n0 + wn * 64 + nf * 16 + lr];
            #pragma unroll
            for (int mf = 0; mf < 8; ++mf)
                #pragma unroll
                for (int rr = 0; rr < 4; ++rr) {
                    float s = 0.f;
                    #pragma unroll
                    for (int nf = 0; nf < 4; ++nf) s += fmaxf(acc[mf][nf][rr], 0.f) * qvv[nf];
                    s += __shfl_xor(s, 1, 64); s += __shfl_xor(s, 2, 64);
                    s += __shfl_xor(s, 4, 64); s += __shfl_xor(s, 8, 64);
                    if (lr == 0)
                        gpart[(size_t)(bxt * 4 + wn) * M +
                              (m0 + wm * 128 + mf * 16 + lk * 4 + rr)] = s;
                }
        }

        #pragma unroll
        for (int mf = 0; mf < 8; ++mf)
            #pragma unroll
            for (int nf = 0; nf < 4; ++nf)
                #pragma unroll
                for (int rr = 0; rr < 4; ++rr) {
                    const int row = m0 + wm * 128 + mf * 16 + lk * 4 + rr;
                    const int col = n0 + wn * 64 + nf * 16 + lr;
                    float v = acc[mf][nf][rr];
                    if constexpr (EPI == 1) v = fmaxf(v, 0.f);
                    if constexpr (EPI == 3) v += __bfloat162float(Xh[(size_t)row * N + col]);
                    if constexpr (WB16) Ob[(size_t)row * N + col] = __float2bfloat16(v);
                    if constexpr (WF32) Of[(size_t)row * N + col] = v;
                }
    }

#undef PHASE
#undef MFMAQ
#undef DS_B
#undef DS_A
}

// ---------------------------------------------------------------------------
// fused weight transposes: 6x [DD<->FF] + lmh [DD][VV] -> bf16 B^T layouts
// ---------------------------------------------------------------------------
__global__ void wtrans_all(const float* __restrict__ e1, const float* __restrict__ e2,
                           const float* __restrict__ b1, const float* __restrict__ b2,
                           const float* __restrict__ d1, const float* __restrict__ d2,
                           const float* __restrict__ lm,
                           bf16* __restrict__ e1T, bf16* __restrict__ e2T,
                           bf16* __restrict__ b1T, bf16* __restrict__ b2T,
                           bf16* __restrict__ d1T, bf16* __restrict__ d2T,
                           bf16* __restrict__ lmT)
{
    int bid = blockIdx.x;
    const float* W; bf16* T; int R, C;
    if (bid < 12288) {
        const int m = bid >> 11;
        bid &= 2047;
        R = (m & 1) ? FF : DD;
        C = (m & 1) ? DD : FF;
        switch (m) {
            case 0:  W = e1; T = e1T; break;
            case 1:  W = e2; T = e2T; break;
            case 2:  W = b1; T = b1T; break;
            case 3:  W = b2; T = b2T; break;
            case 4:  W = d1; T = d1T; break;
            default: W = d2; T = d2T; break;
        }
    } else {
        bid -= 12288; W = lm; T = lmT; R = DD; C = VV;
    }
    const int tc = C >> 5;
    const int cb = (bid % tc) * 32, rb = (bid / tc) * 32;

    __shared__ float tile[32][33];
    const int tx = threadIdx.x & 31, ty = threadIdx.x >> 5;
    #pragma unroll
    for (int i = 0; i < 32; i += 8)
        tile[ty + i][tx] = W[(size_t)(rb + ty + i) * C + cb + tx];
    __syncthreads();
    #pragma unroll
    for (int i = 0; i < 32; i += 8)
        T[(size_t)(cb + ty + i) * R + rb + tx] = __float2bfloat16(tile[tx][ty + i]);
}

// x -> bf16 cast + fused row-dot sx[t] = x[t]·spw  (one wave per token)
__global__ void castx2(const float* __restrict__ x, const float* __restrict__ spw,
                       bf16* __restrict__ xb, float* __restrict__ sx)
{
    const int t  = blockIdx.x * 4 + (threadIdx.x >> 6);
    const int ln = threadIdx.x & 63;
    const float4* row = (const float4*)(x + (size_t)t * DD);
    const float4* sp4 = (const float4*)spw;
    bf16* dst = xb + (size_t)t * DD;
    float s = 0.f;
    #pragma unroll
    for (int q = 0; q < 4; ++q) {
        const int c = q * 64 + ln;
        const float4 v = row[c], p = sp4[c];
        s += v.x * p.x + v.y * p.y + v.z * p.z + v.w * p.w;
        dst[c * 4 + 0] = __float2bfloat16(v.x);
        dst[c * 4 + 1] = __float2bfloat16(v.y);
        dst[c * 4 + 2] = __float2bfloat16(v.z);
        dst[c * 4 + 3] = __float2bfloat16(v.w);
    }
    #pragma unroll
    for (int off = 32; off > 0; off >>= 1) s += __shfl_xor(s, off, 64);
    if (ln == 0) sx[t] = s;
}

// q[f] = sum_d w2[f][d] * sp[d]
__global__ void qvec(const float* __restrict__ w2, const float* __restrict__ sp,
                     float* __restrict__ q)
{
    const int f  = blockIdx.x * 4 + (threadIdx.x >> 6);
    const int ln = threadIdx.x & 63;
    float s = 0.f;
    const float* row = w2 + (size_t)f * DD;
    for (int k = ln; k < DD; k += 64) s += row[k] * sp[k];
    #pragma unroll
    for (int off = 32; off > 0; off >>= 1) s += __shfl_xor(s, off, 64);
    if (ln == 0) q[f] = s;
}

// gate: logit~ = sx + Σ gpart + b ; flag |logit~| < TAU (thread per token)
__global__ void gate2(const float* __restrict__ sx, const float* __restrict__ spb,
                      const float* __restrict__ gpart, float* __restrict__ w,
                      int* __restrict__ mi, int* __restrict__ flags,
                      int* __restrict__ cnt)
{
    const int t = blockIdx.x * 256 + threadIdx.x;
    float s = sx[t] + spb[0];
    #pragma unroll
    for (int j = 0; j < 32; ++j) s += gpart[(size_t)j * TT + t];
    const float sg = 1.f / (1.f + expf(-s));
    w[t]  = sg;
    mi[t] = (sg >= 0.5f) ? 1 : 0;
    if (fabsf(s) < TAU) {
        const int i = atomicAdd(cnt, 1);
        if (i < CAP) flags[i] = t;
    }
}

// split-K exact partial dots for flagged tokens
__global__ __launch_bounds__(256)
void fixh(const float* __restrict__ x, const float* __restrict__ w1,
          const int* __restrict__ flags, const int* __restrict__ cnt,
          float* __restrict__ Hpart)
{
    const int nb = min(*cnt, CAP);
    const int t0 = blockIdx.z * 32;
    if (t0 >= nb) return;
    const int ntk = min(32, nb - t0);
    const int f  = blockIdx.x * 256 + threadIdx.x;
    const int d0 = blockIdx.y * 256;

    __shared__ float xs[32][256];
    for (int i = threadIdx.x; i < 32 * 64; i += 256) {
        const int tk = i >> 6, dq = i & 63;
        float4 v = (tk < ntk)
            ? *(const float4*)&x[(size_t)flags[t0 + tk] * DD + d0 + dq * 4]
            : make_float4(0.f, 0.f, 0.f, 0.f);
        *(float4*)&xs[tk][dq * 4] = v;
    }
    __syncthreads();

    float acc[32];
    #pragma unroll
    for (int tk = 0; tk < 32; ++tk) acc[tk] = 0.f;
    for (int dd = 0; dd < 256; ++dd) {
        const float wv = w1[(size_t)(d0 + dd) * FF + f];
        #pragma unroll
        for (int tk = 0; tk < 32; ++tk) acc[tk] += xs[tk][dd] * wv;
    }
    for (int tk = 0; tk < ntk; ++tk)
        Hpart[((size_t)blockIdx.y * CAP + (t0 + tk)) * FF + f] = acc[tk];
}

// resolve flagged tokens: exact fp32 logit (fixed kc order -> deterministic)
__global__ void fixres2(const float* __restrict__ sx, const float* __restrict__ spb,
                        const float* __restrict__ Hpart, const float* __restrict__ qv,
                        const int* __restrict__ flags, const int* __restrict__ cnt,
                        float* __restrict__ w, int* __restrict__ mi)
{
    const int nb = min(*cnt, CAP);
    const int i  = blockIdx.x * 4 + (threadIdx.x >> 6);
    const int ln = threadIdx.x & 63;
    if (i >= nb) return;                       // wave-uniform
    float s = 0.f;
    for (int f = ln; f < FF; f += 64) {
        const float h = Hpart[(size_t)(0 * CAP + i) * FF + f]
                      + Hpart[(size_t)(1 * CAP + i) * FF + f]
                      + Hpart[(size_t)(2 * CAP + i) * FF + f]
                      + Hpart[(size_t)(3 * CAP + i) * FF + f];
        s += fmaxf(h, 0.f) * qv[f];
    }
    #pragma unroll
    for (int off = 32; off > 0; off >>= 1) s += __shfl_xor(s, off, 64);
    if (ln == 0) {
        const int t = flags[i];
        const float logit = sx[t] + s + spb[0];
        const float sg = 1.f / (1.f + expf(-logit));
        w[t]  = sg;
        mi[t] = (sg >= 0.5f) ? 1 : 0;
    }
}

__global__ void scan_kernel(const int* __restrict__ mi, const int* __restrict__ cu,
                            int* __restrict__ ecs, int* __restrict__ meta)
{
    __shared__ int sums[256];
    const int tid  = threadIdx.x;
    const int base = tid * 64;
    int s = 0;
    for (int i = 0; i < 64; ++i) s += mi[base + i];
    sums[tid] = s;
    __syncthreads();
    for (int off = 1; off < 256; off <<= 1) {
        int v = (tid >= off) ? sums[tid - off] : 0;
        __syncthreads();
        sums[tid] += v;
        __syncthreads();
    }
    int run = (tid == 0) ? 0 : sums[tid - 1];
    for (int i = 0; i < 64; ++i) { ecs[base + i] = run; run += mi[base + i]; }
    if (tid == 255) meta[0] = sums[255];
    if (tid < 4) {
        const int idx = cu[tid];
        const int tc = idx >> 6, rem = idx & 63;
        int e = (tc == 0) ? 0 : sums[tc - 1];
        for (int i = 0; i < rem; ++i) e += mi[tc * 64 + i];
        meta[1 + tid] = e;
    }
}

// pack: Pb[e] = bf16(ENCb[t]*w[t] + pos_emb[rank])   (bf16 in/out)
__global__ void pack_kernel(const bf16* __restrict__ enc, const float* __restrict__ w,
                            const int* __restrict__ mi, const int* __restrict__ ecs,
                            const int* __restrict__ cu, const int* __restrict__ meta,
                            const float* __restrict__ pos_emb, bf16* __restrict__ Pb)
{
    const int t    = blockIdx.x * 4 + (threadIdx.x >> 6);
    const int lane = threadIdx.x & 63;
    if (!mi[t]) return;
    const int e = ecs[t];
    int seg = 0;
    #pragma unroll
    for (int ss = 1; ss < 4; ++ss) if (t >= cu[ss]) seg = ss;
    const int np = e - meta[1 + seg];
    const float wt = w[t];
    const bf16* src = enc + (size_t)t * DD;
    const float4* pe = (const float4*)(pos_emb + (size_t)np * DD);
    bf16* dst = Pb + (size_t)e * DD;
    for (int c = lane; c < DD / 4; c += 64) {
        const float4 p = pe[c];
        dst[c * 4 + 0] = __float2bfloat16(__bfloat162float(src[c * 4 + 0]) * wt + p.x);
        dst[c * 4 + 1] = __float2bfloat16(__bfloat162float(src[c * 4 + 1]) * wt + p.y);
        dst[c * 4 + 2] = __float2bfloat16(__bfloat162float(src[c * 4 + 2]) * wt + p.z);
        dst[c * 4 + 3] = __float2bfloat16(__bfloat162float(src[c * 4 + 3]) * wt + p.w);
    }
}

// combine: Cb[t] = kept ? BBb[ecs[t]] : ENCb[t]   (pure bf16 row copy)
__global__ void combine_kernel(const bf16* __restrict__ ENCb, const bf16* __restrict__ BBb,
                               const int* __restrict__ mi, const int* __restrict__ ecs,
                               bf16* __restrict__ Cb)
{
    const int t    = blockIdx.x * 4 + (threadIdx.x >> 6);
    const int lane = threadIdx.x & 63;
    const bool kept = mi[t] != 0;
    const int4* src = kept ? (const int4*)(BBb + (size_t)ecs[t] * DD)
                           : (const int4*)(ENCb + (size_t)t * DD);
    int4* dst = (int4*)(Cb + (size_t)t * DD);
    #pragma unroll
    for (int q = 0; q < 2; ++q) dst[q * 64 + lane] = src[q * 64 + lane];
}

// ---------------------------------------------------------------------------
extern "C" void kernel_launch(void* const* d_in, const int* in_sizes, int n_in,
                              void* d_out, int out_size, void* d_ws, size_t ws_size,
                              hipStream_t stream)
{
    (void)in_sizes; (void)n_in; (void)out_size; (void)ws_size;
    const float* x   = (const float*)d_in[0];
    const float* ew1 = (const float*)d_in[1];
    const float* ew2 = (const float*)d_in[2];
    const float* bw1 = (const float*)d_in[3];
    const float* bw2 = (const float*)d_in[4];
    const float* dw1 = (const float*)d_in[5];
    const float* dw2 = (const float*)d_in[6];
    const float* spw = (const float*)d_in[7];
    const float* spb = (const float*)d_in[8];
    const float* pem = (const float*)d_in[9];
    const float* lmh = (const float*)d_in[10];
    const int*   cu  = (const int*)d_in[11];
    float* out = (float*)d_out;

    (void)hipFuncSetAttribute((const void*)mgemm8<1, true, false, false, true, 2>,
                              hipFuncAttributeMaxDynamicSharedMemorySize, 131072);
    (void)hipFuncSetAttribute((const void*)mgemm8<3, true, false, false, false, 1>,
                              hipFuncAttributeMaxDynamicSharedMemorySize, 131072);
    (void)hipFuncSetAttribute((const void*)mgemm8<1, true, false, true, false, 2>,
                              hipFuncAttributeMaxDynamicSharedMemorySize, 131072);
    (void)hipFuncSetAttribute((const void*)mgemm8<3, true, false, true, false, 1>,
                              hipFuncAttributeMaxDynamicSharedMemorySize, 131072);
    (void)hipFuncSetAttribute((const void*)mgemm8<1, true, false, false, false, 2>,
                              hipFuncAttributeMaxDynamicSharedMemorySize, 131072);
    (void)hipFuncSetAttribute((const void*)mgemm8<0, false, true, false, false, 4>,
                              hipFuncAttributeMaxDynamicSharedMemorySize, 131072);

    // ---- workspace carve (~260 MB; Hpart aliases BBb) ----
    char* w = (char*)d_ws;
    auto alloc = [&](size_t bytes) { char* p = w; w += bytes; return p; };
    bf16* ew1T = (bf16*)alloc((size_t)FF * DD * 2);
    bf16* ew2T = (bf16*)alloc((size_t)DD * FF * 2);
    bf16* bw1T = (bf16*)alloc((size_t)FF * DD * 2);
    bf16* bw2T = (bf16*)alloc((size_t)DD * FF * 2);
    bf16* dw1T = (bf16*)alloc((size_t)FF * DD * 2);
    bf16* dw2T = (bf16*)alloc((size_t)DD * FF * 2);
    bf16* lmhT = (bf16*)alloc((size_t)VV * DD * 2);
    float* qv  = (float*)alloc((size_t)FF * 4);
    float* GP  = (float*)alloc((size_t)32 * TT * 4);
    float* WG  = (float*)alloc((size_t)TT * 4);
    int*  MI   = (int*)alloc((size_t)TT * 4);
    int*  ECS  = (int*)alloc((size_t)TT * 4);
    int*  META = (int*)alloc(64);
    float* SX  = (float*)alloc((size_t)TT * 4);
    int*  FLAGS= (int*)alloc((size_t)CAP * 4);
    int*  CNT  = (int*)alloc(64);
    bf16* Xb   = (bf16*)alloc((size_t)TT * DD * 2);   // x bf16; reused as Cb
    bf16* Hb   = (bf16*)alloc((size_t)TT * FF * 2);   // hidden (all MLPs)
    bf16* ENCb = (bf16*)alloc((size_t)TT * DD * 2);
    bf16* Pb   = (bf16*)alloc((size_t)TT * DD * 2);   // reused as DECb
    bf16* BBb  = (bf16*)alloc((size_t)TT * DD * 2);
    bf16* Cb   = Xb;           // Xb dead after enc2 residual
    bf16* DECb = Pb;           // Pb dead after bb2
    float* Hpart = (float*)BBb; // 4*CAP*FF*4 = 32 MB, dead before bb2 writes BBb

    const dim3 blk(256);
    const dim3 blk8(512);

    (void)hipMemsetAsync(CNT, 0, 4, stream);

    // ---- prep (separate small launches — round-12 fusion regressed) ----
    castx2<<<TT / 4, blk, 0, stream>>>(x, spw, Xb, SX);
    wtrans_all<<<16384, blk, 0, stream>>>(ew1, ew2, bw1, bw2, dw1, dw2, lmh,
                                          ew1T, ew2T, bw1T, bw2T, dw1T, dw2T, lmhT);
    qvec<<<FF / 4, blk, 0, stream>>>(ew2, spw, qv);

    // ---- encoder GEMM1: bf16 8-phase + fused gate partials (MTILE=2) ----
    mgemm8<1, true, false, false, true, 2><<<dim3(FF / 512, TT / 256), blk8, 131072, stream>>>(
        Xb, ew1T, nullptr, Hb, nullptr, GP, qv, TT, FF, DD, nullptr);

    // ---- gate (approx) + exact borderline fixup + scan ----
    gate2<<<TT / 256, blk, 0, stream>>>(SX, spb, GP, WG, MI, FLAGS, CNT);
    fixh<<<dim3(FF / 256, 4, CAP / 32), blk, 0, stream>>>(x, ew1, FLAGS, CNT, Hpart);
    fixres2<<<CAP / 4, blk, 0, stream>>>(SX, spb, Hpart, qv, FLAGS, CNT, WG, MI);
    scan_kernel<<<1, blk, 0, stream>>>(MI, cu, ECS, META);

    // ---- encoder GEMM2: ENCb = bf16(Hb @ ew2 + Xb) ----
    mgemm8<3, true, false, false, false, 1><<<dim3(DD / 256, TT / 256), blk8, 131072, stream>>>(
        Hb, ew2T, Xb, ENCb, nullptr, nullptr, nullptr, TT, DD, FF, nullptr);

    // ---- pack kept rows (bf16) ----
    pack_kernel<<<TT / 4, blk, 0, stream>>>(ENCb, WG, MI, ECS, cu, META, pem, Pb);

    // ---- backbone (rowlim; bb1 MTILE=2) ----
    mgemm8<1, true, false, true, false, 2><<<dim3(FF / 512, TT / 256), blk8, 131072, stream>>>(
        Pb, bw1T, nullptr, Hb, nullptr, nullptr, nullptr, TT, FF, DD, META);
    mgemm8<3, true, false, true, false, 1><<<dim3(DD / 256, TT / 256), blk8, 131072, stream>>>(
        Hb, bw2T, Pb, BBb, nullptr, nullptr, nullptr, TT, DD, FF, META);

    // ---- scatter-combine (bf16 row select) ----
    combine_kernel<<<TT / 4, blk, 0, stream>>>(ENCb, BBb, MI, ECS, Cb);

    // ---- decoder (dec1 MTILE=2) ----
    mgemm8<1, true, false, false, false, 2><<<dim3(FF / 512, TT / 256), blk8, 131072, stream>>>(
        Cb, dw1T, nullptr, Hb, nullptr, nullptr, nullptr, TT, FF, DD, nullptr);
    mgemm8<3, true, false, false, false, 1><<<dim3(DD / 256, TT / 256), blk8, 131072, stream>>>(
        Hb, dw2T, Cb, DECb, nullptr, nullptr, nullptr, TT, DD, FF, nullptr);

    // ---- lm head (MTILE=4: one 256-block round instead of 4) ----
    mgemm8<0, false, true, false, false, 4><<<dim3(VV / 1024, TT / 256), blk8, 131072, stream>>>(
        DECb, lmhT, nullptr, nullptr, out, nullptr, nullptr, TT, VV, DD, nullptr);
}

// Round 14
// 701.721 us; speedup vs baseline: 1.2365x; 1.2365x over previous
//
#include <hip/hip_runtime.h>
#include <hip/hip_bf16.h>
#include <math.h>
#include <string.h>

static constexpr int TT = 16384;
static constexpr int DD = 1024;
static constexpr int FF = 2048;
static constexpr int VV = 4096;
static constexpr int CAP = 1024;       // borderline-token capacity (exp ~190)
#define TAU 0.02f                      // |logit| flag threshold

using bf16 = __hip_bfloat16;
typedef __attribute__((ext_vector_type(8))) short bf16x8;
typedef __attribute__((ext_vector_type(4))) float f32x4;

__device__ inline void gload16(const void* g, void* l) {
    __builtin_amdgcn_global_load_lds(
        (const __attribute__((address_space(1))) void*)g,
        (__attribute__((address_space(3))) void*)l, 16, 0, 0);
}

// ===========================================================================
// 8-phase 256x256 MFMA GEMM (round-4/7/10 verified schedule, BK=64).
// A [M,K] bf16 row-major, BT [N,K] bf16 (B^T). 512 thr = 8 waves (2M x 4N),
// per-wave out 128x64 (8 mf x 4 nf frags of 16x16x32). BK=64, 2 K-tiles/iter.
// LDS 128 KiB: buf{0,1} x {A[256][64] | B[256][64]}. Stage stream: half j,
// tile=j>>2, part order {B h0, B h1, A h0, A h1}; vmcnt(6) at phases A3/B3.
// EPI: 0 none, 1 relu, 3 +Xbf16.  Staging rows are 128 B (full cache lines).
// NOTE (measured, rounds 8-13): XCD swizzle, BK=32, MTILE persistence, and
// scatter-epilogue fusion ALL regress this configuration — do not re-add.
// ===========================================================================
template<int EPI, bool WB16, bool WF32, bool ROWLIM, bool GPART>
__global__ __launch_bounds__(512, 2)
void mgemm8(const bf16* __restrict__ A, const bf16* __restrict__ BT,
            const bf16* __restrict__ Xh,
            bf16* __restrict__ Ob, float* __restrict__ Of,
            float* __restrict__ gpart, const float* __restrict__ qv,
            int M, int N, int K, const int* __restrict__ rowlim)
{
    if constexpr (ROWLIM) { if ((int)blockIdx.y * 256 >= *rowlim) return; }
    const int m0 = blockIdx.y * 256, n0 = blockIdx.x * 256;

    extern __shared__ char smem[];   // 2 bufs x (A 32K | B 32K) = 128 KiB

    const int tid = threadIdx.x;
    const int wv = tid >> 6, ln = tid & 63;
    const int wm = wv >> 2, wn = wv & 3;
    const int lr = ln & 15, lk = ln >> 4;
    const int swz = (lr & 7) << 4;

    const bf16* Ag = A  + (size_t)m0 * K;
    const bf16* Bg = BT + (size_t)n0 * K;

    const int NT = K >> 6;
    const int NI = NT >> 1;

    const int aoff0 = (wm * 128 + lr) * 128;
    const int boff0 = 32768 + (wn * 64 + lr) * 128;
    const int cb0 = (lk * 16) ^ swz;
    const int cb1 = (64 + lk * 16) ^ swz;

    auto STAGE = [&](const bf16* g, int h, int kt, int buf, int op) {
        const int r = ln >> 3;
        const int c = ((ln & 7) ^ r) * 8;
        const bf16* s = g + (size_t)(h * 128 + wv * 16 + r) * K + kt * 64 + c;
        char* d = smem + buf * 65536 + op * 32768 + h * 16384 + wv * 2048;
        gload16(s, d);
        gload16(s + (size_t)8 * K, d + 1024);
    };
    auto stage_j = [&](int j) {
        const int tile = j >> 2;
        if (tile >= NT) return;
        const int part = j & 3;
        const int buf = tile & 1;
        if (part < 2) STAGE(Bg, part, tile, buf, 1);
        else          STAGE(Ag, part - 2, tile, buf, 0);
    };

    bf16x8 afr[2][2], bfr[4][2];
    f32x4 acc[8][4];
    #pragma unroll
    for (int m = 0; m < 8; ++m)
        #pragma unroll
        for (int n = 0; n < 4; ++n) acc[m][n] = (f32x4){0.f, 0.f, 0.f, 0.f};

#define DS_A(BUF, Q) do {                                                     \
    const char* _p = smem + (BUF) * 65536 + aoff0 + (Q) * 4096;               \
    afr[0][0] = *(const bf16x8*)(_p + cb0);                                   \
    afr[0][1] = *(const bf16x8*)(_p + cb1);                                   \
    afr[1][0] = *(const bf16x8*)(_p + 2048 + cb0);                            \
    afr[1][1] = *(const bf16x8*)(_p + 2048 + cb1);                            \
} while (0)

#define DS_B(BUF) do {                                                        \
    const char* _p = smem + (BUF) * 65536 + boff0;                            \
    _Pragma("unroll")                                                         \
    for (int nf = 0; nf < 4; ++nf) {                                          \
        bfr[nf][0] = *(const bf16x8*)(_p + nf * 2048 + cb0);                  \
        bfr[nf][1] = *(const bf16x8*)(_p + nf * 2048 + cb1);                  \
    }                                                                         \
} while (0)

#define MFMAQ(Q) do {                                                         \
    __builtin_amdgcn_s_setprio(1);                                            \
    _Pragma("unroll")                                                         \
    for (int m2 = 0; m2 < 2; ++m2)                                            \
        _Pragma("unroll")                                                     \
        for (int nf = 0; nf < 4; ++nf) {                                      \
            acc[(Q) * 2 + m2][nf] = __builtin_amdgcn_mfma_f32_16x16x32_bf16(  \
                afr[m2][0], bfr[nf][0], acc[(Q) * 2 + m2][nf], 0, 0, 0);      \
            acc[(Q) * 2 + m2][nf] = __builtin_amdgcn_mfma_f32_16x16x32_bf16(  \
                afr[m2][1], bfr[nf][1], acc[(Q) * 2 + m2][nf], 0, 0, 0);      \
        }                                                                     \
    __builtin_amdgcn_s_setprio(0);                                            \
} while (0)

// W: 0 = no wait, 1 = vmcnt(6), 2 = vmcnt(0)
#define PHASE(Q, BUF, DOB, J, W)                                              \
    {                                                                         \
        DS_A(BUF, Q);                                                         \
        if (DOB) DS_B(BUF);                                                   \
        stage_j(J);                                                           \
        if ((W) == 1)      asm volatile("s_waitcnt vmcnt(6)" ::: "memory");   \
        else if ((W) == 2) asm volatile("s_waitcnt vmcnt(0)" ::: "memory");   \
        __builtin_amdgcn_sched_barrier(0);                                    \
        __builtin_amdgcn_s_barrier();                                         \
        MFMAQ(Q);                                                             \
        __builtin_amdgcn_s_barrier();                                         \
    }

    STAGE(Bg, 0, 0, 0, 1); STAGE(Bg, 1, 0, 0, 1);
    STAGE(Ag, 0, 0, 0, 0); STAGE(Ag, 1, 0, 0, 0);
    asm volatile("s_waitcnt vmcnt(4)" ::: "memory");
    STAGE(Bg, 0, 1, 1, 1); STAGE(Bg, 1, 1, 1, 1);
    STAGE(Ag, 0, 1, 1, 0);
    asm volatile("s_waitcnt vmcnt(6)" ::: "memory");
    __builtin_amdgcn_sched_barrier(0);
    __builtin_amdgcn_s_barrier();

    for (int i = 0; i < NI; ++i) {
        const int jb = 7 + 8 * i;
        const bool last = (i + 1 == NI);
        PHASE(0, 0, true,  jb + 0, 0);
        PHASE(1, 0, false, jb + 1, 0);
        PHASE(2, 0, false, jb + 2, 0);
        PHASE(3, 0, false, jb + 3, last ? 2 : 1);
        PHASE(0, 1, true,  jb + 4, 0);
        PHASE(1, 1, false, jb + 5, 0);
        PHASE(2, 1, false, jb + 6, 0);
        PHASE(3, 1, false, jb + 7, last ? 0 : 1);
    }

#undef PHASE
#undef MFMAQ
#undef DS_B
#undef DS_A

    if constexpr (GPART) {
        float qvv[4];
        #pragma unroll
        for (int nf = 0; nf < 4; ++nf) qvv[nf] = qv[n0 + wn * 64 + nf * 16 + lr];
        #pragma unroll
        for (int mf = 0; mf < 8; ++mf)
            #pragma unroll
            for (int rr = 0; rr < 4; ++rr) {
                float s = 0.f;
                #pragma unroll
                for (int nf = 0; nf < 4; ++nf) s += fmaxf(acc[mf][nf][rr], 0.f) * qvv[nf];
                s += __shfl_xor(s, 1, 64); s += __shfl_xor(s, 2, 64);
                s += __shfl_xor(s, 4, 64); s += __shfl_xor(s, 8, 64);
                if (lr == 0)
                    gpart[(size_t)(blockIdx.x * 4 + wn) * M +
                          (m0 + wm * 128 + mf * 16 + lk * 4 + rr)] = s;
            }
    }

    #pragma unroll
    for (int mf = 0; mf < 8; ++mf)
        #pragma unroll
        for (int nf = 0; nf < 4; ++nf)
            #pragma unroll
            for (int rr = 0; rr < 4; ++rr) {
                const int row = m0 + wm * 128 + mf * 16 + lk * 4 + rr;
                const int col = n0 + wn * 64 + nf * 16 + lr;
                float v = acc[mf][nf][rr];
                if constexpr (EPI == 1) v = fmaxf(v, 0.f);
                if constexpr (EPI == 3) v += __bfloat162float(Xh[(size_t)row * N + col]);
                if constexpr (WB16) Ob[(size_t)row * N + col] = __float2bfloat16(v);
                if constexpr (WF32) Of[(size_t)row * N + col] = v;
            }
}

// ---------------------------------------------------------------------------
// fused weight transposes: 6x [DD<->FF] + lmh [DD][VV] -> bf16 B^T layouts
// ---------------------------------------------------------------------------
__global__ void wtrans_all(const float* __restrict__ e1, const float* __restrict__ e2,
                           const float* __restrict__ b1, const float* __restrict__ b2,
                           const float* __restrict__ d1, const float* __restrict__ d2,
                           const float* __restrict__ lm,
                           bf16* __restrict__ e1T, bf16* __restrict__ e2T,
                           bf16* __restrict__ b1T, bf16* __restrict__ b2T,
                           bf16* __restrict__ d1T, bf16* __restrict__ d2T,
                           bf16* __restrict__ lmT)
{
    int bid = blockIdx.x;
    const float* W; bf16* T; int R, C;
    if (bid < 12288) {
        const int m = bid >> 11;
        bid &= 2047;
        R = (m & 1) ? FF : DD;
        C = (m & 1) ? DD : FF;
        switch (m) {
            case 0:  W = e1; T = e1T; break;
            case 1:  W = e2; T = e2T; break;
            case 2:  W = b1; T = b1T; break;
            case 3:  W = b2; T = b2T; break;
            case 4:  W = d1; T = d1T; break;
            default: W = d2; T = d2T; break;
        }
    } else {
        bid -= 12288; W = lm; T = lmT; R = DD; C = VV;
    }
    const int tc = C >> 5;
    const int cb = (bid % tc) * 32, rb = (bid / tc) * 32;

    __shared__ float tile[32][33];
    const int tx = threadIdx.x & 31, ty = threadIdx.x >> 5;
    #pragma unroll
    for (int i = 0; i < 32; i += 8)
        tile[ty + i][tx] = W[(size_t)(rb + ty + i) * C + cb + tx];
    __syncthreads();
    #pragma unroll
    for (int i = 0; i < 32; i += 8)
        T[(size_t)(cb + ty + i) * R + rb + tx] = __float2bfloat16(tile[tx][ty + i]);
}

// x -> bf16 cast + fused row-dot sx[t] = x[t]·spw  (one wave per token)
__global__ void castx2(const float* __restrict__ x, const float* __restrict__ spw,
                       bf16* __restrict__ xb, float* __restrict__ sx)
{
    const int t  = blockIdx.x * 4 + (threadIdx.x >> 6);
    const int ln = threadIdx.x & 63;
    const float4* row = (const float4*)(x + (size_t)t * DD);
    const float4* sp4 = (const float4*)spw;
    bf16* dst = xb + (size_t)t * DD;
    float s = 0.f;
    #pragma unroll
    for (int q = 0; q < 4; ++q) {
        const int c = q * 64 + ln;
        const float4 v = row[c], p = sp4[c];
        s += v.x * p.x + v.y * p.y + v.z * p.z + v.w * p.w;
        dst[c * 4 + 0] = __float2bfloat16(v.x);
        dst[c * 4 + 1] = __float2bfloat16(v.y);
        dst[c * 4 + 2] = __float2bfloat16(v.z);
        dst[c * 4 + 3] = __float2bfloat16(v.w);
    }
    #pragma unroll
    for (int off = 32; off > 0; off >>= 1) s += __shfl_xor(s, off, 64);
    if (ln == 0) sx[t] = s;
}

// q[f] = sum_d w2[f][d] * sp[d]
__global__ void qvec(const float* __restrict__ w2, const float* __restrict__ sp,
                     float* __restrict__ q)
{
    const int f  = blockIdx.x * 4 + (threadIdx.x >> 6);
    const int ln = threadIdx.x & 63;
    float s = 0.f;
    const float* row = w2 + (size_t)f * DD;
    for (int k = ln; k < DD; k += 64) s += row[k] * sp[k];
    #pragma unroll
    for (int off = 32; off > 0; off >>= 1) s += __shfl_xor(s, off, 64);
    if (ln == 0) q[f] = s;
}

// gate: logit~ = sx + Σ gpart + b ; flag |logit~| < TAU (thread per token)
__global__ void gate2(const float* __restrict__ sx, const float* __restrict__ spb,
                      const float* __restrict__ gpart, float* __restrict__ w,
                      int* __restrict__ mi, int* __restrict__ flags,
                      int* __restrict__ cnt)
{
    const int t = blockIdx.x * 256 + threadIdx.x;
    float s = sx[t] + spb[0];
    #pragma unroll
    for (int j = 0; j < 32; ++j) s += gpart[(size_t)j * TT + t];
    const float sg = 1.f / (1.f + expf(-s));
    w[t]  = sg;
    mi[t] = (sg >= 0.5f) ? 1 : 0;
    if (fabsf(s) < TAU) {
        const int i = atomicAdd(cnt, 1);
        if (i < CAP) flags[i] = t;
    }
}

// split-K exact partial dots for flagged tokens
__global__ __launch_bounds__(256)
void fixh(const float* __restrict__ x, const float* __restrict__ w1,
          const int* __restrict__ flags, const int* __restrict__ cnt,
          float* __restrict__ Hpart)
{
    const int nb = min(*cnt, CAP);
    const int t0 = blockIdx.z * 32;
    if (t0 >= nb) return;
    const int ntk = min(32, nb - t0);
    const int f  = blockIdx.x * 256 + threadIdx.x;
    const int d0 = blockIdx.y * 256;

    __shared__ float xs[32][256];
    for (int i = threadIdx.x; i < 32 * 64; i += 256) {
        const int tk = i >> 6, dq = i & 63;
        float4 v = (tk < ntk)
            ? *(const float4*)&x[(size_t)flags[t0 + tk] * DD + d0 + dq * 4]
            : make_float4(0.f, 0.f, 0.f, 0.f);
        *(float4*)&xs[tk][dq * 4] = v;
    }
    __syncthreads();

    float acc[32];
    #pragma unroll
    for (int tk = 0; tk < 32; ++tk) acc[tk] = 0.f;
    for (int dd = 0; dd < 256; ++dd) {
        const float wv = w1[(size_t)(d0 + dd) * FF + f];
        #pragma unroll
        for (int tk = 0; tk < 32; ++tk) acc[tk] += xs[tk][dd] * wv;
    }
    for (int tk = 0; tk < ntk; ++tk)
        Hpart[((size_t)blockIdx.y * CAP + (t0 + tk)) * FF + f] = acc[tk];
}

// resolve flagged tokens: exact fp32 logit (fixed kc order -> deterministic)
__global__ void fixres2(const float* __restrict__ sx, const float* __restrict__ spb,
                        const float* __restrict__ Hpart, const float* __restrict__ qv,
                        const int* __restrict__ flags, const int* __restrict__ cnt,
                        float* __restrict__ w, int* __restrict__ mi)
{
    const int nb = min(*cnt, CAP);
    const int i  = blockIdx.x * 4 + (threadIdx.x >> 6);
    const int ln = threadIdx.x & 63;
    if (i >= nb) return;                       // wave-uniform
    float s = 0.f;
    for (int f = ln; f < FF; f += 64) {
        const float h = Hpart[(size_t)(0 * CAP + i) * FF + f]
                      + Hpart[(size_t)(1 * CAP + i) * FF + f]
                      + Hpart[(size_t)(2 * CAP + i) * FF + f]
                      + Hpart[(size_t)(3 * CAP + i) * FF + f];
        s += fmaxf(h, 0.f) * qv[f];
    }
    #pragma unroll
    for (int off = 32; off > 0; off >>= 1) s += __shfl_xor(s, off, 64);
    if (ln == 0) {
        const int t = flags[i];
        const float logit = sx[t] + s + spb[0];
        const float sg = 1.f / (1.f + expf(-logit));
        w[t]  = sg;
        mi[t] = (sg >= 0.5f) ? 1 : 0;
    }
}

__global__ void scan_kernel(const int* __restrict__ mi, const int* __restrict__ cu,
                            int* __restrict__ ecs, int* __restrict__ meta)
{
    __shared__ int sums[256];
    const int tid  = threadIdx.x;
    const int base = tid * 64;
    int s = 0;
    for (int i = 0; i < 64; ++i) s += mi[base + i];
    sums[tid] = s;
    __syncthreads();
    for (int off = 1; off < 256; off <<= 1) {
        int v = (tid >= off) ? sums[tid - off] : 0;
        __syncthreads();
        sums[tid] += v;
        __syncthreads();
    }
    int run = (tid == 0) ? 0 : sums[tid - 1];
    for (int i = 0; i < 64; ++i) { ecs[base + i] = run; run += mi[base + i]; }
    if (tid == 255) meta[0] = sums[255];
    if (tid < 4) {
        const int idx = cu[tid];
        const int tc = idx >> 6, rem = idx & 63;
        int e = (tc == 0) ? 0 : sums[tc - 1];
        for (int i = 0; i < rem; ++i) e += mi[tc * 64 + i];
        meta[1 + tid] = e;
    }
}

// pack: Pb[e] = bf16(ENCb[t]*w[t] + pos_emb[rank])   (bf16 in/out)
__global__ void pack_kernel(const bf16* __restrict__ enc, const float* __restrict__ w,
                            const int* __restrict__ mi, const int* __restrict__ ecs,
                            const int* __restrict__ cu, const int* __restrict__ meta,
                            const float* __restrict__ pos_emb, bf16* __restrict__ Pb)
{
    const int t    = blockIdx.x * 4 + (threadIdx.x >> 6);
    const int lane = threadIdx.x & 63;
    if (!mi[t]) return;
    const int e = ecs[t];
    int seg = 0;
    #pragma unroll
    for (int ss = 1; ss < 4; ++ss) if (t >= cu[ss]) seg = ss;
    const int np = e - meta[1 + seg];
    const float wt = w[t];
    const bf16* src = enc + (size_t)t * DD;
    const float4* pe = (const float4*)(pos_emb + (size_t)np * DD);
    bf16* dst = Pb + (size_t)e * DD;
    for (int c = lane; c < DD / 4; c += 64) {
        const float4 p = pe[c];
        dst[c * 4 + 0] = __float2bfloat16(__bfloat162float(src[c * 4 + 0]) * wt + p.x);
        dst[c * 4 + 1] = __float2bfloat16(__bfloat162float(src[c * 4 + 1]) * wt + p.y);
        dst[c * 4 + 2] = __float2bfloat16(__bfloat162float(src[c * 4 + 2]) * wt + p.z);
        dst[c * 4 + 3] = __float2bfloat16(__bfloat162float(src[c * 4 + 3]) * wt + p.w);
    }
}

// combine: Cb[t] = kept ? BBb[ecs[t]] : ENCb[t]   (pure bf16 row copy)
__global__ void combine_kernel(const bf16* __restrict__ ENCb, const bf16* __restrict__ BBb,
                               const int* __restrict__ mi, const int* __restrict__ ecs,
                               bf16* __restrict__ Cb)
{
    const int t    = blockIdx.x * 4 + (threadIdx.x >> 6);
    const int lane = threadIdx.x & 63;
    const bool kept = mi[t] != 0;
    const int4* src = kept ? (const int4*)(BBb + (size_t)ecs[t] * DD)
                           : (const int4*)(ENCb + (size_t)t * DD);
    int4* dst = (int4*)(Cb + (size_t)t * DD);
    #pragma unroll
    for (int q = 0; q < 2; ++q) dst[q * 64 + lane] = src[q * 64 + lane];
}

// ---------------------------------------------------------------------------
extern "C" void kernel_launch(void* const* d_in, const int* in_sizes, int n_in,
                              void* d_out, int out_size, void* d_ws, size_t ws_size,
                              hipStream_t stream)
{
    (void)in_sizes; (void)n_in; (void)out_size; (void)ws_size;
    const float* x   = (const float*)d_in[0];
    const float* ew1 = (const float*)d_in[1];
    const float* ew2 = (const float*)d_in[2];
    const float* bw1 = (const float*)d_in[3];
    const float* bw2 = (const float*)d_in[4];
    const float* dw1 = (const float*)d_in[5];
    const float* dw2 = (const float*)d_in[6];
    const float* spw = (const float*)d_in[7];
    const float* spb = (const float*)d_in[8];
    const float* pem = (const float*)d_in[9];
    const float* lmh = (const float*)d_in[10];
    const int*   cu  = (const int*)d_in[11];
    float* out = (float*)d_out;

    (void)hipFuncSetAttribute((const void*)mgemm8<1, true, false, false, true>,
                              hipFuncAttributeMaxDynamicSharedMemorySize, 131072);
    (void)hipFuncSetAttribute((const void*)mgemm8<3, true, false, false, false>,
                              hipFuncAttributeMaxDynamicSharedMemorySize, 131072);
    (void)hipFuncSetAttribute((const void*)mgemm8<1, true, false, true, false>,
                              hipFuncAttributeMaxDynamicSharedMemorySize, 131072);
    (void)hipFuncSetAttribute((const void*)mgemm8<3, true, false, true, false>,
                              hipFuncAttributeMaxDynamicSharedMemorySize, 131072);
    (void)hipFuncSetAttribute((const void*)mgemm8<1, true, false, false, false>,
                              hipFuncAttributeMaxDynamicSharedMemorySize, 131072);
    (void)hipFuncSetAttribute((const void*)mgemm8<0, false, true, false, false>,
                              hipFuncAttributeMaxDynamicSharedMemorySize, 131072);

    // ---- workspace carve (~260 MB; Hpart aliases BBb) ----
    char* w = (char*)d_ws;
    auto alloc = [&](size_t bytes) { char* p = w; w += bytes; return p; };
    bf16* ew1T = (bf16*)alloc((size_t)FF * DD * 2);
    bf16* ew2T = (bf16*)alloc((size_t)DD * FF * 2);
    bf16* bw1T = (bf16*)alloc((size_t)FF * DD * 2);
    bf16* bw2T = (bf16*)alloc((size_t)DD * FF * 2);
    bf16* dw1T = (bf16*)alloc((size_t)FF * DD * 2);
    bf16* dw2T = (bf16*)alloc((size_t)DD * FF * 2);
    bf16* lmhT = (bf16*)alloc((size_t)VV * DD * 2);
    float* qv  = (float*)alloc((size_t)FF * 4);
    float* GP  = (float*)alloc((size_t)32 * TT * 4);
    float* WG  = (float*)alloc((size_t)TT * 4);
    int*  MI   = (int*)alloc((size_t)TT * 4);
    int*  ECS  = (int*)alloc((size_t)TT * 4);
    int*  META = (int*)alloc(64);
    float* SX  = (float*)alloc((size_t)TT * 4);
    int*  FLAGS= (int*)alloc((size_t)CAP * 4);
    int*  CNT  = (int*)alloc(64);
    bf16* Xb   = (bf16*)alloc((size_t)TT * DD * 2);   // x bf16; reused as Cb
    bf16* Hb   = (bf16*)alloc((size_t)TT * FF * 2);   // hidden (all MLPs)
    bf16* ENCb = (bf16*)alloc((size_t)TT * DD * 2);
    bf16* Pb   = (bf16*)alloc((size_t)TT * DD * 2);   // reused as DECb
    bf16* BBb  = (bf16*)alloc((size_t)TT * DD * 2);
    bf16* Cb   = Xb;           // Xb dead after enc2 residual
    bf16* DECb = Pb;           // Pb dead after bb2
    float* Hpart = (float*)BBb; // 4*CAP*FF*4 = 32 MB, dead before bb2 writes BBb

    const dim3 blk(256);
    const dim3 blk8(512);

    (void)hipMemsetAsync(CNT, 0, 4, stream);

    // ---- prep ----
    castx2<<<TT / 4, blk, 0, stream>>>(x, spw, Xb, SX);
    wtrans_all<<<16384, blk, 0, stream>>>(ew1, ew2, bw1, bw2, dw1, dw2, lmh,
                                          ew1T, ew2T, bw1T, bw2T, dw1T, dw2T, lmhT);
    qvec<<<FF / 4, blk, 0, stream>>>(ew2, spw, qv);

    // ---- encoder GEMM1: bf16 8-phase + fused gate partials ----
    mgemm8<1, true, false, false, true><<<dim3(FF / 256, TT / 256), blk8, 131072, stream>>>(
        Xb, ew1T, nullptr, Hb, nullptr, GP, qv, TT, FF, DD, nullptr);

    // ---- gate (approx) + exact borderline fixup + scan ----
    gate2<<<TT / 256, blk, 0, stream>>>(SX, spb, GP, WG, MI, FLAGS, CNT);
    fixh<<<dim3(FF / 256, 4, CAP / 32), blk, 0, stream>>>(x, ew1, FLAGS, CNT, Hpart);
    fixres2<<<CAP / 4, blk, 0, stream>>>(SX, spb, Hpart, qv, FLAGS, CNT, WG, MI);
    scan_kernel<<<1, blk, 0, stream>>>(MI, cu, ECS, META);

    // ---- encoder GEMM2: ENCb = bf16(Hb @ ew2 + Xb) ----
    mgemm8<3, true, false, false, false><<<dim3(DD / 256, TT / 256), blk8, 131072, stream>>>(
        Hb, ew2T, Xb, ENCb, nullptr, nullptr, nullptr, TT, DD, FF, nullptr);

    // ---- pack kept rows (bf16) ----
    pack_kernel<<<TT / 4, blk, 0, stream>>>(ENCb, WG, MI, ECS, cu, META, pem, Pb);

    // ---- backbone (rowlim) ----
    mgemm8<1, true, false, true, false><<<dim3(FF / 256, TT / 256), blk8, 131072, stream>>>(
        Pb, bw1T, nullptr, Hb, nullptr, nullptr, nullptr, TT, FF, DD, META);
    mgemm8<3, true, false, true, false><<<dim3(DD / 256, TT / 256), blk8, 131072, stream>>>(
        Hb, bw2T, Pb, BBb, nullptr, nullptr, nullptr, TT, DD, FF, META);

    // ---- scatter-combine (bf16 row select) ----
    combine_kernel<<<TT / 4, blk, 0, stream>>>(ENCb, BBb, MI, ECS, Cb);

    // ---- decoder ----
    mgemm8<1, true, false, false, false><<<dim3(FF / 256, TT / 256), blk8, 131072, stream>>>(
        Cb, dw1T, nullptr, Hb, nullptr, nullptr, nullptr, TT, FF, DD, nullptr);
    mgemm8<3, true, false, false, false><<<dim3(DD / 256, TT / 256), blk8, 131072, stream>>>(
        Hb, dw2T, Cb, DECb, nullptr, nullptr, nullptr, TT, DD, FF, nullptr);

    // ---- lm head ----
    mgemm8<0, false, true, false, false><<<dim3(VV / 256, TT / 256), blk8, 131072, stream>>>(
        DECb, lmhT, nullptr, nullptr, out, nullptr, nullptr, TT, VV, DD, nullptr);
}